// Round 6
// baseline (232.989 us; speedup 1.0000x reference)
//
#include <hip/hip_runtime.h>
#include <cstdint>

#define B_ 8
#define N_ 512
#define M_ 512
#define D_ 512
#define F_ 512
#define H_ 8
#define DH_ 64
#define FH_ 64

// DPP-based partial reduce (VALU pipe). bound_ctrl=true.
template <int CTRL>
__device__ __forceinline__ float dpp_add(float x) {
    int y = __builtin_amdgcn_update_dpp(0, __float_as_int(x), CTRL, 0xf, 0xf, true);
    return x + __int_as_float(y);
}

// K2 (fused K1): per (h,n): Q1 = gelu(X*diag(W1)); logits = Q1·W2^T; softmax; A.
__global__ __launch_bounds__(256, 4) void syn_k_attn(const float* __restrict__ X,
                                                     const float* __restrict__ W1,
                                                     const float* __restrict__ W2,
                                                     float* __restrict__ A) {
    int hn = blockIdx.x;
    int h = hn >> 9, n = hn & 511;
    int t = threadIdx.x;
    int wave = t >> 6, lane = t & 63;
    __shared__ float q1s[8 * 68];        // [b][d], stride 68
    __shared__ float logits[8 * 520];    // [b][m], stride 520

    // Phase 1: Q1 for this (h,n)
    {
        int d = t & 63;
        int b0 = t >> 6;
        float w = W1[(size_t)hn * (DH_ * DH_) + d * (DH_ + 1)];
        #pragma unroll
        for (int i = 0; i < 2; ++i) {
            int bi = b0 + i * 4;
            float x = X[((size_t)(bi * N_ + n)) * D_ + h * DH_ + d];
            float v = x * w;
            q1s[bi * 68 + d] = 0.5f * v * (1.0f + erff(v * 0.70710678118654752440f));
        }
    }
    __syncthreads();

    int mr = lane >> 3, c = lane & 7;
    float4 qa[8], qb[8];
    #pragma unroll
    for (int b = 0; b < 8; ++b) {
        qa[b] = *(const float4*)&q1s[b * 68 + c * 8];
        qb[b] = *(const float4*)&q1s[b * 68 + c * 8 + 4];
    }

    const float* w2 = W2 + (size_t)hn * ((size_t)M_ * DH_);
    #pragma unroll 4
    for (int g = 0; g < 16; ++g) {
        int m = (wave + g * 4) * 8 + mr;
        const float* wr = w2 + (size_t)m * DH_ + c * 8;
        float4 wa = *(const float4*)wr;
        float4 wb = *(const float4*)(wr + 4);
        float acc[8];
        #pragma unroll
        for (int b = 0; b < 8; ++b) {
            float a0 = wa.x * qa[b].x + wa.y * qa[b].y + wa.z * qa[b].z + wa.w * qa[b].w
                     + wb.x * qb[b].x + wb.y * qb[b].y + wb.z * qb[b].z + wb.w * qb[b].w;
            a0 = dpp_add<0xB1>(a0);    // + lane^1 (quad_perm)
            a0 = dpp_add<0x4E>(a0);    // + lane^2 (quad_perm)
            a0 = dpp_add<0x124>(a0);   // row_ror:4 — valid on (lane%16)<4 i.e. c<4
            acc[b] = a0;
        }
        float lo = c == 0 ? acc[0] : c == 1 ? acc[1] : c == 2 ? acc[2] : acc[3];
        float hi = c == 0 ? acc[4] : c == 1 ? acc[5] : c == 2 ? acc[6] : acc[7];
        if (c < 4) {
            logits[c * 520 + m] = lo;
            logits[(c + 4) * 520 + m] = hi;
        }
    }
    __syncthreads();

    // Phase 3: softmax over m; wave handles rows b = wave, wave+4
    for (int bb = wave; bb < 8; bb += 4) {
        const float* lrow = &logits[bb * 520 + lane * 8];
        float4 va = *(const float4*)lrow;
        float4 vb = *(const float4*)(lrow + 4);
        float v[8] = {va.x, va.y, va.z, va.w, vb.x, vb.y, vb.z, vb.w};
        float mx = v[0];
        #pragma unroll
        for (int i = 1; i < 8; ++i) mx = fmaxf(mx, v[i]);
        #pragma unroll
        for (int s = 1; s < 64; s <<= 1) mx = fmaxf(mx, __shfl_xor(mx, s));
        float e[8]; float sum = 0.f;
        #pragma unroll
        for (int i = 0; i < 8; ++i) { e[i] = expf(v[i] - mx); sum += e[i]; }
        #pragma unroll
        for (int s = 1; s < 64; s <<= 1) sum += __shfl_xor(sum, s);
        float inv = 1.0f / sum;
        float* outp = A + ((size_t)(bb * H_ + h) * N_ + n) * M_ + lane * 8;
        float4 o0 = make_float4(e[0] * inv, e[1] * inv, e[2] * inv, e[3] * inv);
        float4 o1 = make_float4(e[4] * inv, e[5] * inv, e[6] * inv, e[7] * inv);
        *(float4*)outp = o0;
        *(float4*)(outp + 4) = o1;
    }
}

// Swizzled transposed tile: addr(k, r) = k*64 + 4*(((r>>2) ^ (k>>2)) & 15) + (r&3).
// Double-buffered schedule (1 barrier / K-step):
//   regs = G(0); for s: { store regs->buf[s&1]; barrier; regs = G(s+1); compute buf[s&1]; }

// K3: per (b,h): Y[n,f] = (A[n,:]·Vh[:,f]) * WVdiag[f]. 64x64 tile, 4x4/thread.
__global__ __launch_bounds__(256, 2) void syn_k_pv(const float* __restrict__ A,
                                                   const float* __restrict__ V,
                                                   const float* __restrict__ WV,
                                                   float* __restrict__ Y) {
    int bh = blockIdx.y;
    int b = bh >> 3, h = bh & 7;
    int n0 = blockIdx.x * 64;
    int t = threadIdx.x;
    int tx = t & 15, ty = t >> 4;
    int kk = tx * 4;
    __shared__ float Alds[2][64 * 64];   // swizzled [m][n]
    __shared__ float Vlds[2][64 * 64];   // natural  [m][f]
    float acc[4][4] = {};
    const float* Abase = A + ((size_t)bh * N_ + n0) * M_;
    const float* Vbase = V + (size_t)b * ((size_t)M_ * F_) + h * FH_;

    float4 ra[4], rv[4];
    #pragma unroll
    for (int it = 0; it < 4; ++it) {
        int r = ty + it * 16;
        ra[it] = *(const float4*)(Abase + (size_t)r * M_ + kk);
        rv[it] = *(const float4*)(Vbase + (size_t)r * F_ + kk);
    }

    #pragma unroll 1
    for (int s = 0; s < 8; ++s) {
        float* Ab = Alds[s & 1];
        float* Vb = Vlds[s & 1];
        int slot = ((ty >> 2) ^ tx) & 15;   // note: r = ty + it*16 -> (r>>2)&15 varies with it
        #pragma unroll
        for (int it = 0; it < 4; ++it) {
            int r = ty + it * 16;
            int sl = ((r >> 2) ^ tx) & 15;
            float* p = &Ab[kk * 64 + sl * 4 + (r & 3)];
            p[0] = ra[it].x; p[64] = ra[it].y; p[128] = ra[it].z; p[192] = ra[it].w;
            *(float4*)&Vb[r * 64 + kk] = rv[it];
        }
        (void)slot;
        __syncthreads();
        if (s < 7) {
            int m0 = (s + 1) * 64;
            #pragma unroll
            for (int it = 0; it < 4; ++it) {
                int r = ty + it * 16;
                ra[it] = *(const float4*)(Abase + (size_t)r * M_ + m0 + kk);
                rv[it] = *(const float4*)(Vbase + (size_t)(m0 + r) * F_ + kk);
            }
        }
        #pragma unroll 2
        for (int k4 = 0; k4 < 16; ++k4) {
            int sa = ((ty ^ k4) & 15) * 4;
            #pragma unroll
            for (int kj = 0; kj < 4; ++kj) {
                int k = k4 * 4 + kj;
                float4 a4 = *(const float4*)&Ab[k * 64 + sa];
                float4 v4 = *(const float4*)&Vb[k * 64 + tx * 4];
                float ar[4] = {a4.x, a4.y, a4.z, a4.w};
                float vr[4] = {v4.x, v4.y, v4.z, v4.w};
                #pragma unroll
                for (int i = 0; i < 4; ++i)
                    #pragma unroll
                    for (int j = 0; j < 4; ++j)
                        acc[i][j] += ar[i] * vr[j];
            }
        }
    }
    float s_[4];
    #pragma unroll
    for (int j = 0; j < 4; ++j)
        s_[j] = WV[(size_t)h * (FH_ * FH_) + (tx * 4 + j) * (FH_ + 1)];
    #pragma unroll
    for (int i = 0; i < 4; ++i) {
        int row = n0 + ty * 4 + i;
        float4 o = make_float4(acc[i][0] * s_[0], acc[i][1] * s_[1],
                               acc[i][2] * s_[2], acc[i][3] * s_[3]);
        *(float4*)(Y + ((size_t)(b * N_ + row)) * F_ + h * FH_ + tx * 4) = o;
    }
}

// K4: out[r,f'] = Y[r,:]·Ow[f',:] + Ob[f'].  64x64 tile, 4x4/thread.
__global__ __launch_bounds__(256, 2) void syn_k_out(const float* __restrict__ Yg,
                                                    const float* __restrict__ Ow,
                                                    const float* __restrict__ Ob,
                                                    float* __restrict__ out) {
    int r0 = blockIdx.y * 64;
    int f0 = blockIdx.x * 64;
    int t = threadIdx.x;
    int tx = t & 15, ty = t >> 4;
    int kk = tx * 4;
    __shared__ float Ylds[2][64 * 64];   // swizzled [k][r]
    __shared__ float Wlds[2][64 * 64];   // swizzled [k][f']
    float acc[4][4] = {};

    float4 ry[4], rw[4];
    #pragma unroll
    for (int it = 0; it < 4; ++it) {
        int r = ty + it * 16;
        ry[it] = *(const float4*)(Yg + (size_t)(r0 + r) * F_ + kk);
        rw[it] = *(const float4*)(Ow + (size_t)(f0 + r) * F_ + kk);
    }

    #pragma unroll 1
    for (int s = 0; s < 8; ++s) {
        float* Yb = Ylds[s & 1];
        float* Wb = Wlds[s & 1];
        #pragma unroll
        for (int it = 0; it < 4; ++it) {
            int r = ty + it * 16;
            int sl = ((r >> 2) ^ tx) & 15;
            float* py = &Yb[kk * 64 + sl * 4 + (r & 3)];
            py[0] = ry[it].x; py[64] = ry[it].y; py[128] = ry[it].z; py[192] = ry[it].w;
            float* pw = &Wb[kk * 64 + sl * 4 + (r & 3)];
            pw[0] = rw[it].x; pw[64] = rw[it].y; pw[128] = rw[it].z; pw[192] = rw[it].w;
        }
        __syncthreads();
        if (s < 7) {
            int k0 = (s + 1) * 64;
            #pragma unroll
            for (int it = 0; it < 4; ++it) {
                int r = ty + it * 16;
                ry[it] = *(const float4*)(Yg + (size_t)(r0 + r) * F_ + k0 + kk);
                rw[it] = *(const float4*)(Ow + (size_t)(f0 + r) * F_ + k0 + kk);
            }
        }
        #pragma unroll 2
        for (int k4 = 0; k4 < 16; ++k4) {
            int sy = ((ty ^ k4) & 15) * 4;
            int sw = ((tx ^ k4) & 15) * 4;
            #pragma unroll
            for (int kj = 0; kj < 4; ++kj) {
                int k = k4 * 4 + kj;
                float4 y4 = *(const float4*)&Yb[k * 64 + sy];
                float4 w4 = *(const float4*)&Wb[k * 64 + sw];
                float yr[4] = {y4.x, y4.y, y4.z, y4.w};
                float wr[4] = {w4.x, w4.y, w4.z, w4.w};
                #pragma unroll
                for (int i = 0; i < 4; ++i)
                    #pragma unroll
                    for (int j = 0; j < 4; ++j)
                        acc[i][j] += yr[i] * wr[j];
            }
        }
    }
    float bb[4];
    #pragma unroll
    for (int j = 0; j < 4; ++j) bb[j] = Ob[f0 + tx * 4 + j];
    #pragma unroll
    for (int i = 0; i < 4; ++i) {
        int row = r0 + ty * 4 + i;
        float4 o = make_float4(acc[i][0] + bb[0], acc[i][1] + bb[1],
                               acc[i][2] + bb[2], acc[i][3] + bb[3]);
        *(float4*)(out + (size_t)row * F_ + f0 + tx * 4) = o;
    }
}

extern "C" void kernel_launch(void* const* d_in, const int* in_sizes, int n_in,
                              void* d_out, int out_size, void* d_ws, size_t ws_size,
                              hipStream_t stream) {
    const float* X  = (const float*)d_in[0];
    const float* V  = (const float*)d_in[1];
    const float* W1 = (const float*)d_in[2];
    const float* W2 = (const float*)d_in[3];
    const float* WV = (const float*)d_in[4];
    const float* Ow = (const float*)d_in[5];
    const float* Ob = (const float*)d_in[6];
    float* out = (float*)d_out;

    float* ws = (float*)d_ws;
    float* A  = ws;                                   // B*H*N*M = 16.78M floats
    float* Y  = A + (size_t)B_ * H_ * N_ * M_;        // B*N*F   = 2.1M floats

    syn_k_attn<<<H_ * N_, 256, 0, stream>>>(X, W1, W2, A);
    syn_k_pv<<<dim3(N_ / 64, B_ * H_), 256, 0, stream>>>(A, V, WV, Y);
    syn_k_out<<<dim3(F_ / 64, (B_ * N_) / 64), 256, 0, stream>>>(Y, Ow, Ob, out);
}

// Round 7
// 207.020 us; speedup vs baseline: 1.1254x; 1.1254x over previous
//
#include <hip/hip_runtime.h>
#include <cstdint>

#define B_ 8
#define N_ 512
#define M_ 512
#define D_ 512
#define F_ 512
#define H_ 8
#define DH_ 64
#define FH_ 64

// DPP-based partial reduce (VALU pipe). bound_ctrl=true.
template <int CTRL>
__device__ __forceinline__ float dpp_add(float x) {
    int y = __builtin_amdgcn_update_dpp(0, __float_as_int(x), CTRL, 0xf, 0xf, true);
    return x + __int_as_float(y);
}

// K2 (fused K1): per (h,n): Q1 = gelu(X*diag(W1)); logits = Q1·W2^T; softmax; A.
__global__ __launch_bounds__(256, 4) void syn_k_attn(const float* __restrict__ X,
                                                     const float* __restrict__ W1,
                                                     const float* __restrict__ W2,
                                                     float* __restrict__ A) {
    int hn = blockIdx.x;
    int h = hn >> 9, n = hn & 511;
    int t = threadIdx.x;
    int wave = t >> 6, lane = t & 63;
    __shared__ float q1s[8 * 68];        // [b][d], stride 68
    __shared__ float logits[8 * 520];    // [b][m], stride 520

    // Phase 1: Q1 for this (h,n)
    {
        int d = t & 63;
        int b0 = t >> 6;
        float w = W1[(size_t)hn * (DH_ * DH_) + d * (DH_ + 1)];
        #pragma unroll
        for (int i = 0; i < 2; ++i) {
            int bi = b0 + i * 4;
            float x = X[((size_t)(bi * N_ + n)) * D_ + h * DH_ + d];
            float v = x * w;
            q1s[bi * 68 + d] = 0.5f * v * (1.0f + erff(v * 0.70710678118654752440f));
        }
    }
    __syncthreads();

    int mr = lane >> 3, c = lane & 7;
    float4 qa[8], qb[8];
    #pragma unroll
    for (int b = 0; b < 8; ++b) {
        qa[b] = *(const float4*)&q1s[b * 68 + c * 8];
        qb[b] = *(const float4*)&q1s[b * 68 + c * 8 + 4];
    }

    const float* w2 = W2 + (size_t)hn * ((size_t)M_ * DH_);
    #pragma unroll 4
    for (int g = 0; g < 16; ++g) {
        int m = (wave + g * 4) * 8 + mr;
        const float* wr = w2 + (size_t)m * DH_ + c * 8;
        float4 wa = *(const float4*)wr;
        float4 wb = *(const float4*)(wr + 4);
        float acc[8];
        #pragma unroll
        for (int b = 0; b < 8; ++b) {
            float a0 = wa.x * qa[b].x + wa.y * qa[b].y + wa.z * qa[b].z + wa.w * qa[b].w
                     + wb.x * qb[b].x + wb.y * qb[b].y + wb.z * qb[b].z + wb.w * qb[b].w;
            a0 = dpp_add<0xB1>(a0);    // + lane^1 (quad_perm)
            a0 = dpp_add<0x4E>(a0);    // + lane^2 (quad_perm)
            a0 = dpp_add<0x124>(a0);   // row_ror:4 — valid on (lane%16)<4 i.e. c<4
            acc[b] = a0;
        }
        float lo = c == 0 ? acc[0] : c == 1 ? acc[1] : c == 2 ? acc[2] : acc[3];
        float hi = c == 0 ? acc[4] : c == 1 ? acc[5] : c == 2 ? acc[6] : acc[7];
        if (c < 4) {
            logits[c * 520 + m] = lo;
            logits[(c + 4) * 520 + m] = hi;
        }
    }
    __syncthreads();

    // Phase 3: softmax over m; wave handles rows b = wave, wave+4
    for (int bb = wave; bb < 8; bb += 4) {
        const float* lrow = &logits[bb * 520 + lane * 8];
        float4 va = *(const float4*)lrow;
        float4 vb = *(const float4*)(lrow + 4);
        float v[8] = {va.x, va.y, va.z, va.w, vb.x, vb.y, vb.z, vb.w};
        float mx = v[0];
        #pragma unroll
        for (int i = 1; i < 8; ++i) mx = fmaxf(mx, v[i]);
        #pragma unroll
        for (int s = 1; s < 64; s <<= 1) mx = fmaxf(mx, __shfl_xor(mx, s));
        float e[8]; float sum = 0.f;
        #pragma unroll
        for (int i = 0; i < 8; ++i) { e[i] = expf(v[i] - mx); sum += e[i]; }
        #pragma unroll
        for (int s = 1; s < 64; s <<= 1) sum += __shfl_xor(sum, s);
        float inv = 1.0f / sum;
        float* outp = A + ((size_t)(bb * H_ + h) * N_ + n) * M_ + lane * 8;
        float4 o0 = make_float4(e[0] * inv, e[1] * inv, e[2] * inv, e[3] * inv);
        float4 o1 = make_float4(e[4] * inv, e[5] * inv, e[6] * inv, e[7] * inv);
        *(float4*)outp = o0;
        *(float4*)(outp + 4) = o1;
    }
}

// Swizzled transposed tile: addr(k, r) = k*64 + 4*(((r>>2) ^ (k>>2)) & 15) + (r&3).
// Writes: 2-way bank alias (free). b128 reads: 16B-aligned, conflict-free.

// K3: per (b,h): Y[n,f] = (A[n,:]·Vh[:,f]) * WVdiag[f]. 64x64 tile, 4x4/thread.
__global__ __launch_bounds__(256) void syn_k_pv(const float* __restrict__ A,
                                                const float* __restrict__ V,
                                                const float* __restrict__ WV,
                                                float* __restrict__ Y) {
    int bh = blockIdx.y;
    int b = bh >> 3, h = bh & 7;
    int n0 = blockIdx.x * 64;
    int t = threadIdx.x;
    int tx = t & 15, ty = t >> 4;
    __shared__ float Alds[64 * 64];   // swizzled [m][n]
    __shared__ float Vlds[64 * 64];   // natural  [m][f]
    float acc[4][4] = {};
    const float* Abase = A + ((size_t)bh * N_ + n0) * M_;
    const float* Vbase = V + (size_t)b * ((size_t)M_ * F_) + h * FH_;
    int kk = tx * 4;
    for (int m0 = 0; m0 < M_; m0 += 64) {
        #pragma unroll
        for (int it = 0; it < 4; ++it) {
            int r = ty + it * 16;
            float4 a4 = *(const float4*)(Abase + (size_t)r * M_ + m0 + kk);
            int slot = ((r >> 2) ^ tx) & 15;
            float* p = &Alds[kk * 64 + slot * 4 + (r & 3)];
            p[0] = a4.x; p[64] = a4.y; p[128] = a4.z; p[192] = a4.w;
            float4 v4 = *(const float4*)(Vbase + (size_t)(m0 + r) * F_ + kk);
            *(float4*)&Vlds[r * 64 + kk] = v4;
        }
        __syncthreads();
        #pragma unroll 2
        for (int k4 = 0; k4 < 16; ++k4) {
            int sa = ((ty ^ k4) & 15) * 4;
            #pragma unroll
            for (int kj = 0; kj < 4; ++kj) {
                int k = k4 * 4 + kj;
                float4 a4 = *(const float4*)&Alds[k * 64 + sa];
                float4 v4 = *(const float4*)&Vlds[k * 64 + tx * 4];
                float ar[4] = {a4.x, a4.y, a4.z, a4.w};
                float vr[4] = {v4.x, v4.y, v4.z, v4.w};
                #pragma unroll
                for (int i = 0; i < 4; ++i)
                    #pragma unroll
                    for (int j = 0; j < 4; ++j)
                        acc[i][j] += ar[i] * vr[j];
            }
        }
        __syncthreads();
    }
    float s_[4];
    #pragma unroll
    for (int j = 0; j < 4; ++j)
        s_[j] = WV[(size_t)h * (FH_ * FH_) + (tx * 4 + j) * (FH_ + 1)];
    #pragma unroll
    for (int i = 0; i < 4; ++i) {
        int row = n0 + ty * 4 + i;
        float4 o = make_float4(acc[i][0] * s_[0], acc[i][1] * s_[1],
                               acc[i][2] * s_[2], acc[i][3] * s_[3]);
        *(float4*)(Y + ((size_t)(b * N_ + row)) * F_ + h * FH_ + tx * 4) = o;
    }
}

// K4 (hybrid layout): out[r,f'] = Y[r,:]·Ow[f',:] + Ob[f'].  64x64 tile, 4x4/thread.
// Y natural [r][k] (float4 stores, broadcast reads); Ow swizzle-transposed [k][f'].
__global__ __launch_bounds__(256) void syn_k_out(const float* __restrict__ Yg,
                                                 const float* __restrict__ Ow,
                                                 const float* __restrict__ Ob,
                                                 float* __restrict__ out) {
    int r0 = blockIdx.y * 64;
    int f0 = blockIdx.x * 64;
    int t = threadIdx.x;
    int tx = t & 15, ty = t >> 4;
    __shared__ float Ylds[64 * 68];   // natural [r][k], stride 68
    __shared__ float Wlds[64 * 64];   // swizzled [k][f']
    float acc[4][4] = {};
    int kk = tx * 4;
    for (int k0 = 0; k0 < F_; k0 += 64) {
        #pragma unroll
        for (int it = 0; it < 4; ++it) {
            int r = ty + it * 16;
            float4 y4 = *(const float4*)(Yg + (size_t)(r0 + r) * F_ + k0 + kk);
            *(float4*)&Ylds[r * 68 + kk] = y4;
            int sl = ((r >> 2) ^ tx) & 15;
            float4 w4 = *(const float4*)(Ow + (size_t)(f0 + r) * F_ + k0 + kk);
            float* pw = &Wlds[kk * 64 + sl * 4 + (r & 3)];
            pw[0] = w4.x; pw[64] = w4.y; pw[128] = w4.z; pw[192] = w4.w;
        }
        __syncthreads();
        #pragma unroll 2
        for (int k4 = 0; k4 < 16; ++k4) {
            int sw = ((tx ^ k4) & 15) * 4;
            float ya[4][4];
            #pragma unroll
            for (int i = 0; i < 4; ++i) {
                float4 y4 = *(const float4*)&Ylds[(ty * 4 + i) * 68 + k4 * 4];
                ya[i][0] = y4.x; ya[i][1] = y4.y; ya[i][2] = y4.z; ya[i][3] = y4.w;
            }
            #pragma unroll
            for (int kj = 0; kj < 4; ++kj) {
                float4 w4 = *(const float4*)&Wlds[(k4 * 4 + kj) * 64 + sw];
                float wr[4] = {w4.x, w4.y, w4.z, w4.w};
                #pragma unroll
                for (int i = 0; i < 4; ++i)
                    #pragma unroll
                    for (int j = 0; j < 4; ++j)
                        acc[i][j] += ya[i][kj] * wr[j];
            }
        }
        __syncthreads();
    }
    float bb[4];
    #pragma unroll
    for (int j = 0; j < 4; ++j) bb[j] = Ob[f0 + tx * 4 + j];
    #pragma unroll
    for (int i = 0; i < 4; ++i) {
        int row = r0 + ty * 4 + i;
        float4 o = make_float4(acc[i][0] + bb[0], acc[i][1] + bb[1],
                               acc[i][2] + bb[2], acc[i][3] + bb[3]);
        *(float4*)(out + (size_t)row * F_ + f0 + tx * 4) = o;
    }
}

extern "C" void kernel_launch(void* const* d_in, const int* in_sizes, int n_in,
                              void* d_out, int out_size, void* d_ws, size_t ws_size,
                              hipStream_t stream) {
    const float* X  = (const float*)d_in[0];
    const float* V  = (const float*)d_in[1];
    const float* W1 = (const float*)d_in[2];
    const float* W2 = (const float*)d_in[3];
    const float* WV = (const float*)d_in[4];
    const float* Ow = (const float*)d_in[5];
    const float* Ob = (const float*)d_in[6];
    float* out = (float*)d_out;

    float* ws = (float*)d_ws;
    float* A  = ws;                                   // B*H*N*M = 16.78M floats
    float* Y  = A + (size_t)B_ * H_ * N_ * M_;        // B*N*F   = 2.1M floats

    syn_k_attn<<<H_ * N_, 256, 0, stream>>>(X, W1, W2, A);
    syn_k_pv<<<dim3(N_ / 64, B_ * H_), 256, 0, stream>>>(A, V, WV, Y);
    syn_k_out<<<dim3(F_ / 64, (B_ * N_) / 64), 256, 0, stream>>>(Y, Ow, Ob, out);
}

// Round 8
// 200.420 us; speedup vs baseline: 1.1625x; 1.0329x over previous
//
#include <hip/hip_runtime.h>
#include <cstdint>

#define B_ 8
#define N_ 512
#define M_ 512
#define D_ 512
#define F_ 512
#define H_ 8
#define DH_ 64
#define FH_ 64

typedef __attribute__((ext_vector_type(8))) short bf16x8;
typedef __attribute__((ext_vector_type(4))) float f32x4;

// RNE float -> bf16 bits, and back
__device__ __forceinline__ unsigned short f2bf(float x) {
    unsigned u = __float_as_uint(x);
    return (unsigned short)((u + 0x7fffu + ((u >> 16) & 1u)) >> 16);
}
__device__ __forceinline__ float bf2f(unsigned short b) {
    return __uint_as_float(((unsigned)b) << 16);
}

// DPP-based partial reduce (VALU pipe). bound_ctrl=true.
template <int CTRL>
__device__ __forceinline__ float dpp_add(float x) {
    int y = __builtin_amdgcn_update_dpp(0, __float_as_int(x), CTRL, 0xf, 0xf, true);
    return x + __int_as_float(y);
}

// K2 (fused K1): per (h,n): Q1 = gelu(X*diag(W1)); logits = Q1·W2^T; softmax; A.
__global__ __launch_bounds__(256, 4) void syn_k_attn(const float* __restrict__ X,
                                                     const float* __restrict__ W1,
                                                     const float* __restrict__ W2,
                                                     float* __restrict__ A) {
    int hn = blockIdx.x;
    int h = hn >> 9, n = hn & 511;
    int t = threadIdx.x;
    int wave = t >> 6, lane = t & 63;
    __shared__ float q1s[8 * 68];        // [b][d], stride 68
    __shared__ float logits[8 * 520];    // [b][m], stride 520

    // Phase 1: Q1 for this (h,n)
    {
        int d = t & 63;
        int b0 = t >> 6;
        float w = W1[(size_t)hn * (DH_ * DH_) + d * (DH_ + 1)];
        #pragma unroll
        for (int i = 0; i < 2; ++i) {
            int bi = b0 + i * 4;
            float x = X[((size_t)(bi * N_ + n)) * D_ + h * DH_ + d];
            float v = x * w;
            q1s[bi * 68 + d] = 0.5f * v * (1.0f + erff(v * 0.70710678118654752440f));
        }
    }
    __syncthreads();

    int mr = lane >> 3, c = lane & 7;
    float4 qa[8], qb[8];
    #pragma unroll
    for (int b = 0; b < 8; ++b) {
        qa[b] = *(const float4*)&q1s[b * 68 + c * 8];
        qb[b] = *(const float4*)&q1s[b * 68 + c * 8 + 4];
    }

    const float* w2 = W2 + (size_t)hn * ((size_t)M_ * DH_);
    #pragma unroll 4
    for (int g = 0; g < 16; ++g) {
        int m = (wave + g * 4) * 8 + mr;
        const float* wr = w2 + (size_t)m * DH_ + c * 8;
        float4 wa = *(const float4*)wr;
        float4 wb = *(const float4*)(wr + 4);
        float acc[8];
        #pragma unroll
        for (int b = 0; b < 8; ++b) {
            float a0 = wa.x * qa[b].x + wa.y * qa[b].y + wa.z * qa[b].z + wa.w * qa[b].w
                     + wb.x * qb[b].x + wb.y * qb[b].y + wb.z * qb[b].z + wb.w * qb[b].w;
            a0 = dpp_add<0xB1>(a0);    // + lane^1 (quad_perm)
            a0 = dpp_add<0x4E>(a0);    // + lane^2 (quad_perm)
            a0 = dpp_add<0x124>(a0);   // row_ror:4 — valid on (lane%16)<4 i.e. c<4
            acc[b] = a0;
        }
        float lo = c == 0 ? acc[0] : c == 1 ? acc[1] : c == 2 ? acc[2] : acc[3];
        float hi = c == 0 ? acc[4] : c == 1 ? acc[5] : c == 2 ? acc[6] : acc[7];
        if (c < 4) {
            logits[c * 520 + m] = lo;
            logits[(c + 4) * 520 + m] = hi;
        }
    }
    __syncthreads();

    // Phase 3: softmax over m; wave handles rows b = wave, wave+4
    for (int bb = wave; bb < 8; bb += 4) {
        const float* lrow = &logits[bb * 520 + lane * 8];
        float4 va = *(const float4*)lrow;
        float4 vb = *(const float4*)(lrow + 4);
        float v[8] = {va.x, va.y, va.z, va.w, vb.x, vb.y, vb.z, vb.w};
        float mx = v[0];
        #pragma unroll
        for (int i = 1; i < 8; ++i) mx = fmaxf(mx, v[i]);
        #pragma unroll
        for (int s = 1; s < 64; s <<= 1) mx = fmaxf(mx, __shfl_xor(mx, s));
        float e[8]; float sum = 0.f;
        #pragma unroll
        for (int i = 0; i < 8; ++i) { e[i] = expf(v[i] - mx); sum += e[i]; }
        #pragma unroll
        for (int s = 1; s < 64; s <<= 1) sum += __shfl_xor(sum, s);
        float inv = 1.0f / sum;
        float* outp = A + ((size_t)(bb * H_ + h) * N_ + n) * M_ + lane * 8;
        float4 o0 = make_float4(e[0] * inv, e[1] * inv, e[2] * inv, e[3] * inv);
        float4 o1 = make_float4(e[4] * inv, e[5] * inv, e[6] * inv, e[7] * inv);
        *(float4*)outp = o0;
        *(float4*)(outp + 4) = o1;
    }
}

// K3: per (b,h): Y[n,f] = (A[n,:]·Vh[:,f]) * WVdiag[f]. 64x64 tile, 4x4/thread.
// Epilogue now emits split-bf16 Yhi/Ylo for the MFMA K4.
__global__ __launch_bounds__(256) void syn_k_pv(const float* __restrict__ A,
                                                const float* __restrict__ V,
                                                const float* __restrict__ WV,
                                                unsigned short* __restrict__ Yhi,
                                                unsigned short* __restrict__ Ylo) {
    int bh = blockIdx.y;
    int b = bh >> 3, h = bh & 7;
    int n0 = blockIdx.x * 64;
    int t = threadIdx.x;
    int tx = t & 15, ty = t >> 4;
    __shared__ float Alds[64 * 64];   // swizzled [m][n]
    __shared__ float Vlds[64 * 64];   // natural  [m][f]
    float acc[4][4] = {};
    const float* Abase = A + ((size_t)bh * N_ + n0) * M_;
    const float* Vbase = V + (size_t)b * ((size_t)M_ * F_) + h * FH_;
    int kk = tx * 4;
    for (int m0 = 0; m0 < M_; m0 += 64) {
        #pragma unroll
        for (int it = 0; it < 4; ++it) {
            int r = ty + it * 16;
            float4 a4 = *(const float4*)(Abase + (size_t)r * M_ + m0 + kk);
            int slot = ((r >> 2) ^ tx) & 15;
            float* p = &Alds[kk * 64 + slot * 4 + (r & 3)];
            p[0] = a4.x; p[64] = a4.y; p[128] = a4.z; p[192] = a4.w;
            float4 v4 = *(const float4*)(Vbase + (size_t)(m0 + r) * F_ + kk);
            *(float4*)&Vlds[r * 64 + kk] = v4;
        }
        __syncthreads();
        #pragma unroll 2
        for (int k4 = 0; k4 < 16; ++k4) {
            int sa = ((ty ^ k4) & 15) * 4;
            #pragma unroll
            for (int kj = 0; kj < 4; ++kj) {
                int k = k4 * 4 + kj;
                float4 a4 = *(const float4*)&Alds[k * 64 + sa];
                float4 v4 = *(const float4*)&Vlds[k * 64 + tx * 4];
                float ar[4] = {a4.x, a4.y, a4.z, a4.w};
                float vr[4] = {v4.x, v4.y, v4.z, v4.w};
                #pragma unroll
                for (int i = 0; i < 4; ++i)
                    #pragma unroll
                    for (int j = 0; j < 4; ++j)
                        acc[i][j] += ar[i] * vr[j];
            }
        }
        __syncthreads();
    }
    float s_[4];
    #pragma unroll
    for (int j = 0; j < 4; ++j)
        s_[j] = WV[(size_t)h * (FH_ * FH_) + (tx * 4 + j) * (FH_ + 1)];
    #pragma unroll
    for (int i = 0; i < 4; ++i) {
        int row = n0 + ty * 4 + i;
        float ys[4];
        #pragma unroll
        for (int j = 0; j < 4; ++j) ys[j] = acc[i][j] * s_[j];
        unsigned short hb[4], lb[4];
        #pragma unroll
        for (int j = 0; j < 4; ++j) {
            hb[j] = f2bf(ys[j]);
            lb[j] = f2bf(ys[j] - bf2f(hb[j]));
        }
        size_t base = ((size_t)(b * N_ + row)) * F_ + h * FH_ + tx * 4;
        uint2 hv, lv;
        hv.x = (unsigned)hb[0] | ((unsigned)hb[1] << 16);
        hv.y = (unsigned)hb[2] | ((unsigned)hb[3] << 16);
        lv.x = (unsigned)lb[0] | ((unsigned)lb[1] << 16);
        lv.y = (unsigned)lb[2] | ((unsigned)lb[3] << 16);
        *(uint2*)(Yhi + base) = hv;
        *(uint2*)(Ylo + base) = lv;
    }
}

// Split Ow into bf16 hi/lo arrays. 512*512 elems, 4/thread, grid 256.
__global__ __launch_bounds__(256) void syn_k_splitw(const float* __restrict__ Ow,
                                                    unsigned short* __restrict__ Whi,
                                                    unsigned short* __restrict__ Wlo) {
    int i = (blockIdx.x * 256 + threadIdx.x) * 4;
    float4 v = *(const float4*)(Ow + i);
    float vv[4] = {v.x, v.y, v.z, v.w};
    unsigned short hb[4], lb[4];
    #pragma unroll
    for (int j = 0; j < 4; ++j) {
        hb[j] = f2bf(vv[j]);
        lb[j] = f2bf(vv[j] - bf2f(hb[j]));
    }
    uint2 hv, lv;
    hv.x = (unsigned)hb[0] | ((unsigned)hb[1] << 16);
    hv.y = (unsigned)hb[2] | ((unsigned)hb[3] << 16);
    lv.x = (unsigned)lb[0] | ((unsigned)lb[1] << 16);
    lv.y = (unsigned)lb[2] | ((unsigned)lb[3] << 16);
    *(uint2*)(Whi + i) = hv;
    *(uint2*)(Wlo + i) = lv;
}

// K4 (split-bf16 MFMA): out = Yhi·Whi^T + Yhi·Wlo^T + Ylo·Whi^T + Ob.
// 64x64 tile, 4 waves (2x2), each wave 32x32 via 2x2 16x16x32 fragments.
// LDS: row-major [64 rows][8 kgroups of 8 bf16], slot = kg ^ (row&7) swizzle.
__global__ __launch_bounds__(256) void syn_k_out_mfma(const unsigned short* __restrict__ Yhi,
                                                      const unsigned short* __restrict__ Ylo,
                                                      const unsigned short* __restrict__ Whi,
                                                      const unsigned short* __restrict__ Wlo,
                                                      const float* __restrict__ Ob,
                                                      float* __restrict__ out) {
    int r0 = blockIdx.x * 64;
    int f0 = blockIdx.y * 64;
    int t = threadIdx.x;
    int lane = t & 63, wave = t >> 6;
    int wr = wave >> 1, wc = wave & 1;
    __shared__ __align__(16) unsigned short Al[64 * 64];
    __shared__ __align__(16) unsigned short Bl[64 * 64];
    f32x4 acc[2][2];
    #pragma unroll
    for (int i = 0; i < 2; ++i)
        #pragma unroll
        for (int j = 0; j < 2; ++j)
            acc[i][j] = (f32x4){0.f, 0.f, 0.f, 0.f};

    const unsigned short* Aseg[3] = {Yhi, Yhi, Ylo};
    const unsigned short* Bseg[3] = {Whi, Wlo, Whi};

    int srow = t >> 3, skg = t & 7;          // staging: thread covers rows srow, srow+32
    int sslot = skg ^ (srow & 7);            // (srow+32)&7 == srow&7
    unsigned aoff0 = srow * 64 + sslot * 8;
    unsigned aoff1 = (srow + 32) * 64 + sslot * 8;

    for (int seg = 0; seg < 3; ++seg) {
        const unsigned short* Ag0 = Aseg[seg] + (size_t)(r0 + srow) * 512 + skg * 8;
        const unsigned short* Ag1 = Aseg[seg] + (size_t)(r0 + srow + 32) * 512 + skg * 8;
        const unsigned short* Bg0 = Bseg[seg] + (size_t)(f0 + srow) * 512 + skg * 8;
        const unsigned short* Bg1 = Bseg[seg] + (size_t)(f0 + srow + 32) * 512 + skg * 8;
        #pragma unroll 1
        for (int kb = 0; kb < 512; kb += 64) {
            float4 a0 = *(const float4*)(Ag0 + kb);
            float4 a1 = *(const float4*)(Ag1 + kb);
            float4 b0 = *(const float4*)(Bg0 + kb);
            float4 b1 = *(const float4*)(Bg1 + kb);
            *(float4*)&Al[aoff0] = a0;
            *(float4*)&Al[aoff1] = a1;
            *(float4*)&Bl[aoff0] = b0;
            *(float4*)&Bl[aoff1] = b1;
            __syncthreads();
            #pragma unroll
            for (int m = 0; m < 2; ++m) {
                int kslot = (m * 4 + (lane >> 4)) ^ (lane & 7);
                bf16x8 af[2], bfr[2];
                #pragma unroll
                for (int q = 0; q < 2; ++q) {
                    int arow = wr * 32 + q * 16 + (lane & 15);
                    af[q] = *(const bf16x8*)&Al[arow * 64 + kslot * 8];
                    int brow = wc * 32 + q * 16 + (lane & 15);
                    bfr[q] = *(const bf16x8*)&Bl[brow * 64 + kslot * 8];
                }
                #pragma unroll
                for (int i = 0; i < 2; ++i)
                    #pragma unroll
                    for (int j = 0; j < 2; ++j)
                        acc[i][j] = __builtin_amdgcn_mfma_f32_16x16x32_bf16(
                            af[i], bfr[j], acc[i][j], 0, 0, 0);
            }
            __syncthreads();
        }
    }

    // epilogue: D reg r -> row=(lane>>4)*4+r, col=lane&15
    int crow = r0 + wr * 32 + (lane >> 4) * 4;
    int ccol = f0 + wc * 32 + (lane & 15);
    float ob0 = Ob[ccol], ob1 = Ob[ccol + 16];
    #pragma unroll
    for (int i = 0; i < 2; ++i)
        #pragma unroll
        for (int j = 0; j < 2; ++j) {
            float obv = (j == 0) ? ob0 : ob1;
            #pragma unroll
            for (int r = 0; r < 4; ++r) {
                int row = crow + i * 16 + r;
                out[(size_t)row * F_ + ccol + j * 16] = acc[i][j][r] + obv;
            }
        }
}

extern "C" void kernel_launch(void* const* d_in, const int* in_sizes, int n_in,
                              void* d_out, int out_size, void* d_ws, size_t ws_size,
                              hipStream_t stream) {
    const float* X  = (const float*)d_in[0];
    const float* V  = (const float*)d_in[1];
    const float* W1 = (const float*)d_in[2];
    const float* W2 = (const float*)d_in[3];
    const float* WV = (const float*)d_in[4];
    const float* Ow = (const float*)d_in[5];
    const float* Ob = (const float*)d_in[6];
    float* out = (float*)d_out;

    float* ws = (float*)d_ws;
    float* A = ws;                                             // B*H*N*M floats
    unsigned short* Yhi = (unsigned short*)(A + (size_t)B_ * H_ * N_ * M_);
    unsigned short* Ylo = Yhi + (size_t)B_ * N_ * F_;
    unsigned short* Whi = Ylo + (size_t)B_ * N_ * F_;
    unsigned short* Wlo = Whi + (size_t)F_ * F_;

    syn_k_splitw<<<(F_ * F_) / (256 * 4), 256, 0, stream>>>(Ow, Whi, Wlo);
    syn_k_attn<<<H_ * N_, 256, 0, stream>>>(X, W1, W2, A);
    syn_k_pv<<<dim3(N_ / 64, B_ * H_), 256, 0, stream>>>(A, V, WV, Yhi, Ylo);
    syn_k_out_mfma<<<dim3((B_ * N_) / 64, F_ / 64), 256, 0, stream>>>(Yhi, Ylo, Whi, Wlo, Ob, out);
}

// Round 9
// 190.729 us; speedup vs baseline: 1.2216x; 1.0508x over previous
//
#include <hip/hip_runtime.h>
#include <cstdint>

#define B_ 8
#define N_ 512
#define M_ 512
#define D_ 512
#define F_ 512
#define H_ 8
#define DH_ 64
#define FH_ 64

typedef __attribute__((ext_vector_type(8))) short bf16x8;
typedef __attribute__((ext_vector_type(4))) float f32x4;
typedef __attribute__((ext_vector_type(8))) unsigned short u16x8;

// RNE float -> bf16 bits, and back
__device__ __forceinline__ unsigned short f2bf(float x) {
    unsigned u = __float_as_uint(x);
    return (unsigned short)((u + 0x7fffu + ((u >> 16) & 1u)) >> 16);
}
__device__ __forceinline__ float bf2f(unsigned short b) {
    return __uint_as_float(((unsigned)b) << 16);
}

// DPP-based partial reduce (VALU pipe). bound_ctrl=true.
template <int CTRL>
__device__ __forceinline__ float dpp_add(float x) {
    int y = __builtin_amdgcn_update_dpp(0, __float_as_int(x), CTRL, 0xf, 0xf, true);
    return x + __int_as_float(y);
}

// K2 (fused K1): per (h,n): Q1 = gelu(X*diag(W1)); logits = Q1·W2^T; softmax; A.
__global__ __launch_bounds__(256, 4) void syn_k_attn(const float* __restrict__ X,
                                                     const float* __restrict__ W1,
                                                     const float* __restrict__ W2,
                                                     float* __restrict__ A) {
    int hn = blockIdx.x;
    int h = hn >> 9, n = hn & 511;
    int t = threadIdx.x;
    int wave = t >> 6, lane = t & 63;
    __shared__ float q1s[8 * 68];        // [b][d], stride 68
    __shared__ float logits[8 * 520];    // [b][m], stride 520

    {
        int d = t & 63;
        int b0 = t >> 6;
        float w = W1[(size_t)hn * (DH_ * DH_) + d * (DH_ + 1)];
        #pragma unroll
        for (int i = 0; i < 2; ++i) {
            int bi = b0 + i * 4;
            float x = X[((size_t)(bi * N_ + n)) * D_ + h * DH_ + d];
            float v = x * w;
            q1s[bi * 68 + d] = 0.5f * v * (1.0f + erff(v * 0.70710678118654752440f));
        }
    }
    __syncthreads();

    int mr = lane >> 3, c = lane & 7;
    float4 qa[8], qb[8];
    #pragma unroll
    for (int b = 0; b < 8; ++b) {
        qa[b] = *(const float4*)&q1s[b * 68 + c * 8];
        qb[b] = *(const float4*)&q1s[b * 68 + c * 8 + 4];
    }

    const float* w2 = W2 + (size_t)hn * ((size_t)M_ * DH_);
    #pragma unroll 4
    for (int g = 0; g < 16; ++g) {
        int m = (wave + g * 4) * 8 + mr;
        const float* wr = w2 + (size_t)m * DH_ + c * 8;
        float4 wa = *(const float4*)wr;
        float4 wb = *(const float4*)(wr + 4);
        float acc[8];
        #pragma unroll
        for (int b = 0; b < 8; ++b) {
            float a0 = wa.x * qa[b].x + wa.y * qa[b].y + wa.z * qa[b].z + wa.w * qa[b].w
                     + wb.x * qb[b].x + wb.y * qb[b].y + wb.z * qb[b].z + wb.w * qb[b].w;
            a0 = dpp_add<0xB1>(a0);
            a0 = dpp_add<0x4E>(a0);
            a0 = dpp_add<0x124>(a0);
            acc[b] = a0;
        }
        float lo = c == 0 ? acc[0] : c == 1 ? acc[1] : c == 2 ? acc[2] : acc[3];
        float hi = c == 0 ? acc[4] : c == 1 ? acc[5] : c == 2 ? acc[6] : acc[7];
        if (c < 4) {
            logits[c * 520 + m] = lo;
            logits[(c + 4) * 520 + m] = hi;
        }
    }
    __syncthreads();

    for (int bb = wave; bb < 8; bb += 4) {
        const float* lrow = &logits[bb * 520 + lane * 8];
        float4 va = *(const float4*)lrow;
        float4 vb = *(const float4*)(lrow + 4);
        float v[8] = {va.x, va.y, va.z, va.w, vb.x, vb.y, vb.z, vb.w};
        float mx = v[0];
        #pragma unroll
        for (int i = 1; i < 8; ++i) mx = fmaxf(mx, v[i]);
        #pragma unroll
        for (int s = 1; s < 64; s <<= 1) mx = fmaxf(mx, __shfl_xor(mx, s));
        float e[8]; float sum = 0.f;
        #pragma unroll
        for (int i = 0; i < 8; ++i) { e[i] = expf(v[i] - mx); sum += e[i]; }
        #pragma unroll
        for (int s = 1; s < 64; s <<= 1) sum += __shfl_xor(sum, s);
        float inv = 1.0f / sum;
        float* outp = A + ((size_t)(bb * H_ + h) * N_ + n) * M_ + lane * 8;
        float4 o0 = make_float4(e[0] * inv, e[1] * inv, e[2] * inv, e[3] * inv);
        float4 o1 = make_float4(e[4] * inv, e[5] * inv, e[6] * inv, e[7] * inv);
        *(float4*)outp = o0;
        *(float4*)(outp + 4) = o1;
    }
}

// Split Ow into bf16 hi/lo arrays. 512*512 elems, 4/thread, grid 256.
__global__ __launch_bounds__(256) void syn_k_splitw(const float* __restrict__ Ow,
                                                    unsigned short* __restrict__ Whi,
                                                    unsigned short* __restrict__ Wlo) {
    int i = (blockIdx.x * 256 + threadIdx.x) * 4;
    float4 v = *(const float4*)(Ow + i);
    float vv[4] = {v.x, v.y, v.z, v.w};
    unsigned short hb[4], lb[4];
    #pragma unroll
    for (int j = 0; j < 4; ++j) {
        hb[j] = f2bf(vv[j]);
        lb[j] = f2bf(vv[j] - bf2f(hb[j]));
    }
    uint2 hv, lv;
    hv.x = (unsigned)hb[0] | ((unsigned)hb[1] << 16);
    hv.y = (unsigned)hb[2] | ((unsigned)hb[3] << 16);
    lv.x = (unsigned)lb[0] | ((unsigned)lb[1] << 16);
    lv.y = (unsigned)lb[2] | ((unsigned)lb[3] << 16);
    *(uint2*)(Whi + i) = hv;
    *(uint2*)(Wlo + i) = lv;
}

// splitv: Vt_hi/lo[(bh*64+f)*512 + m] = split(V[b][m][h*64+f]). LDS transpose.
__global__ __launch_bounds__(256) void syn_k_splitv(const float* __restrict__ V,
                                                    unsigned short* __restrict__ Vthi,
                                                    unsigned short* __restrict__ Vtlo) {
    int bh = blockIdx.x;
    int b = bh >> 3, h = bh & 7;
    int t = threadIdx.x;
    __shared__ float lds[64 * 68];
    for (int m0 = 0; m0 < M_; m0 += 64) {
        int m = t >> 2, fo = (t & 3) * 16;
        const float* src = V + ((size_t)(b * M_ + m0 + m)) * F_ + h * FH_ + fo;
        #pragma unroll
        for (int i = 0; i < 4; ++i)
            *(float4*)&lds[m * 68 + fo + i * 4] = *(const float4*)(src + i * 4);
        __syncthreads();
        int f = t >> 2, mo = (t & 3) * 16;
        unsigned short hb[16], lb[16];
        #pragma unroll
        for (int i = 0; i < 16; ++i) {
            float x = lds[(mo + i) * 68 + f];
            hb[i] = f2bf(x);
            lb[i] = f2bf(x - bf2f(hb[i]));
        }
        size_t base = ((size_t)(bh * 64 + f)) * 512 + m0 + mo;
        *(u16x8*)(Vthi + base) = *(u16x8*)hb;
        *(u16x8*)(Vthi + base + 8) = *(u16x8*)&hb[8];
        *(u16x8*)(Vtlo + base) = *(u16x8*)lb;
        *(u16x8*)(Vtlo + base + 8) = *(u16x8*)&lb[8];
        __syncthreads();
    }
}

// K3 (split-bf16 MFMA): Y[n,f] = (Σ_m A[n,m]·Vt[f,m]) * WVdiag[f], emit Yhi/Ylo.
// 64x64 tile, 4 waves 2x2, K=512 over m, 3 segments from ONE staging per k-block.
__global__ __launch_bounds__(256) void syn_k_pv_mfma(const float* __restrict__ A,
                                                     const unsigned short* __restrict__ Vthi,
                                                     const unsigned short* __restrict__ Vtlo,
                                                     const float* __restrict__ WV,
                                                     unsigned short* __restrict__ Yhi,
                                                     unsigned short* __restrict__ Ylo) {
    int bh = blockIdx.y;                 // = b*H + h, matches A layout
    int b = bh >> 3, h = bh & 7;
    int n0 = blockIdx.x * 64;
    int t = threadIdx.x;
    int lane = t & 63, wave = t >> 6;
    int wr = wave >> 1, wc = wave & 1;
    __shared__ __align__(16) unsigned short Alh[64 * 64], All[64 * 64];
    __shared__ __align__(16) unsigned short Blh[64 * 64], Bll[64 * 64];
    f32x4 acc[2][2];
    #pragma unroll
    for (int i = 0; i < 2; ++i)
        #pragma unroll
        for (int j = 0; j < 2; ++j) acc[i][j] = (f32x4){0.f, 0.f, 0.f, 0.f};

    int srow = t >> 3, skg = t & 7;
    int sslot = skg ^ (srow & 7);
    const float* Abase = A + ((size_t)bh * N_ + n0) * M_;
    const unsigned short* Vhb = Vthi + ((size_t)bh * 64) * 512;
    const unsigned short* Vlb = Vtlo + ((size_t)bh * 64) * 512;

    #pragma unroll 1
    for (int mb = 0; mb < 8; ++mb) {
        int m0 = mb * 64;
        #pragma unroll
        for (int rr = 0; rr < 2; ++rr) {
            int row = srow + rr * 32;
            const float* ap = Abase + (size_t)row * M_ + m0 + skg * 8;
            float4 x0 = *(const float4*)ap;
            float4 x1 = *(const float4*)(ap + 4);
            float xs[8] = {x0.x, x0.y, x0.z, x0.w, x1.x, x1.y, x1.z, x1.w};
            unsigned short hb[8], lb[8];
            #pragma unroll
            for (int i = 0; i < 8; ++i) {
                hb[i] = f2bf(xs[i]);
                lb[i] = f2bf(xs[i] - bf2f(hb[i]));
            }
            *(u16x8*)&Alh[row * 64 + sslot * 8] = *(u16x8*)hb;
            *(u16x8*)&All[row * 64 + sslot * 8] = *(u16x8*)lb;
            *(u16x8*)&Blh[row * 64 + sslot * 8] =
                *(const u16x8*)(Vhb + (size_t)row * 512 + m0 + skg * 8);
            *(u16x8*)&Bll[row * 64 + sslot * 8] =
                *(const u16x8*)(Vlb + (size_t)row * 512 + m0 + skg * 8);
        }
        __syncthreads();
        #pragma unroll
        for (int mg = 0; mg < 2; ++mg) {
            int kslot = (mg * 4 + (lane >> 4)) ^ (lane & 7);
            bf16x8 afh[2], afl[2], bfh[2], bfl[2];
            #pragma unroll
            for (int q = 0; q < 2; ++q) {
                int arow = wr * 32 + q * 16 + (lane & 15);
                afh[q] = *(const bf16x8*)&Alh[arow * 64 + kslot * 8];
                afl[q] = *(const bf16x8*)&All[arow * 64 + kslot * 8];
                int brow = wc * 32 + q * 16 + (lane & 15);
                bfh[q] = *(const bf16x8*)&Blh[brow * 64 + kslot * 8];
                bfl[q] = *(const bf16x8*)&Bll[brow * 64 + kslot * 8];
            }
            #pragma unroll
            for (int i = 0; i < 2; ++i)
                #pragma unroll
                for (int j = 0; j < 2; ++j) {
                    acc[i][j] = __builtin_amdgcn_mfma_f32_16x16x32_bf16(afh[i], bfh[j], acc[i][j], 0, 0, 0);
                    acc[i][j] = __builtin_amdgcn_mfma_f32_16x16x32_bf16(afh[i], bfl[j], acc[i][j], 0, 0, 0);
                    acc[i][j] = __builtin_amdgcn_mfma_f32_16x16x32_bf16(afl[i], bfh[j], acc[i][j], 0, 0, 0);
                }
        }
        __syncthreads();
    }

    int crow = n0 + wr * 32 + (lane >> 4) * 4;
    int ccol = wc * 32 + (lane & 15);
    #pragma unroll
    for (int j = 0; j < 2; ++j) {
        int f = ccol + j * 16;
        float s = WV[(size_t)h * (FH_ * FH_) + f * (FH_ + 1)];
        #pragma unroll
        for (int i = 0; i < 2; ++i)
            #pragma unroll
            for (int r = 0; r < 4; ++r) {
                int row = crow + i * 16 + r;
                float y = acc[i][j][r] * s;
                unsigned short hb = f2bf(y);
                unsigned short lb = f2bf(y - bf2f(hb));
                size_t base = ((size_t)(b * N_ + row)) * F_ + h * FH_ + f;
                Yhi[base] = hb;
                Ylo[base] = lb;
            }
    }
}

// K4 (split-bf16 MFMA): out = Yhi·Whi^T + Yhi·Wlo^T + Ylo·Whi^T + Ob.
// Stage all 4 panels once per k-block; 3 segments from LDS.
__global__ __launch_bounds__(256) void syn_k_out_mfma(const unsigned short* __restrict__ Yhi,
                                                      const unsigned short* __restrict__ Ylo,
                                                      const unsigned short* __restrict__ Whi,
                                                      const unsigned short* __restrict__ Wlo,
                                                      const float* __restrict__ Ob,
                                                      float* __restrict__ out) {
    int r0 = blockIdx.x * 64;
    int f0 = blockIdx.y * 64;
    int t = threadIdx.x;
    int lane = t & 63, wave = t >> 6;
    int wr = wave >> 1, wc = wave & 1;
    __shared__ __align__(16) unsigned short Alh[64 * 64], All[64 * 64];
    __shared__ __align__(16) unsigned short Blh[64 * 64], Bll[64 * 64];
    f32x4 acc[2][2];
    #pragma unroll
    for (int i = 0; i < 2; ++i)
        #pragma unroll
        for (int j = 0; j < 2; ++j) acc[i][j] = (f32x4){0.f, 0.f, 0.f, 0.f};

    int srow = t >> 3, skg = t & 7;
    int sslot = skg ^ (srow & 7);

    #pragma unroll 1
    for (int kb = 0; kb < 512; kb += 64) {
        #pragma unroll
        for (int rr = 0; rr < 2; ++rr) {
            int row = srow + rr * 32;
            size_t ya = (size_t)(r0 + row) * 512 + kb + skg * 8;
            size_t wa = (size_t)(f0 + row) * 512 + kb + skg * 8;
            *(u16x8*)&Alh[row * 64 + sslot * 8] = *(const u16x8*)(Yhi + ya);
            *(u16x8*)&All[row * 64 + sslot * 8] = *(const u16x8*)(Ylo + ya);
            *(u16x8*)&Blh[row * 64 + sslot * 8] = *(const u16x8*)(Whi + wa);
            *(u16x8*)&Bll[row * 64 + sslot * 8] = *(const u16x8*)(Wlo + wa);
        }
        __syncthreads();
        #pragma unroll
        for (int mg = 0; mg < 2; ++mg) {
            int kslot = (mg * 4 + (lane >> 4)) ^ (lane & 7);
            bf16x8 afh[2], afl[2], bfh[2], bfl[2];
            #pragma unroll
            for (int q = 0; q < 2; ++q) {
                int arow = wr * 32 + q * 16 + (lane & 15);
                afh[q] = *(const bf16x8*)&Alh[arow * 64 + kslot * 8];
                afl[q] = *(const bf16x8*)&All[arow * 64 + kslot * 8];
                int brow = wc * 32 + q * 16 + (lane & 15);
                bfh[q] = *(const bf16x8*)&Blh[brow * 64 + kslot * 8];
                bfl[q] = *(const bf16x8*)&Bll[brow * 64 + kslot * 8];
            }
            #pragma unroll
            for (int i = 0; i < 2; ++i)
                #pragma unroll
                for (int j = 0; j < 2; ++j) {
                    acc[i][j] = __builtin_amdgcn_mfma_f32_16x16x32_bf16(afh[i], bfh[j], acc[i][j], 0, 0, 0);
                    acc[i][j] = __builtin_amdgcn_mfma_f32_16x16x32_bf16(afh[i], bfl[j], acc[i][j], 0, 0, 0);
                    acc[i][j] = __builtin_amdgcn_mfma_f32_16x16x32_bf16(afl[i], bfh[j], acc[i][j], 0, 0, 0);
                }
        }
        __syncthreads();
    }

    int crow = r0 + wr * 32 + (lane >> 4) * 4;
    int ccol = f0 + wc * 32 + (lane & 15);
    float ob0 = Ob[ccol], ob1 = Ob[ccol + 16];
    #pragma unroll
    for (int i = 0; i < 2; ++i)
        #pragma unroll
        for (int j = 0; j < 2; ++j) {
            float obv = (j == 0) ? ob0 : ob1;
            #pragma unroll
            for (int r = 0; r < 4; ++r) {
                int row = crow + i * 16 + r;
                out[(size_t)row * F_ + ccol + j * 16] = acc[i][j][r] + obv;
            }
        }
}

extern "C" void kernel_launch(void* const* d_in, const int* in_sizes, int n_in,
                              void* d_out, int out_size, void* d_ws, size_t ws_size,
                              hipStream_t stream) {
    const float* X  = (const float*)d_in[0];
    const float* V  = (const float*)d_in[1];
    const float* W1 = (const float*)d_in[2];
    const float* W2 = (const float*)d_in[3];
    const float* WV = (const float*)d_in[4];
    const float* Ow = (const float*)d_in[5];
    const float* Ob = (const float*)d_in[6];
    float* out = (float*)d_out;

    float* ws = (float*)d_ws;
    float* A = ws;                                             // 67MB
    unsigned short* Yhi = (unsigned short*)(A + (size_t)B_ * H_ * N_ * M_);
    unsigned short* Ylo = Yhi + (size_t)B_ * N_ * F_;
    unsigned short* Whi = Ylo + (size_t)B_ * N_ * F_;
    unsigned short* Wlo = Whi + (size_t)F_ * F_;
    unsigned short* Vthi = Wlo + (size_t)F_ * F_;
    unsigned short* Vtlo = Vthi + (size_t)B_ * H_ * FH_ * M_;

    syn_k_splitw<<<(F_ * F_) / (256 * 4), 256, 0, stream>>>(Ow, Whi, Wlo);
    syn_k_splitv<<<B_ * H_, 256, 0, stream>>>(V, Vthi, Vtlo);
    syn_k_attn<<<H_ * N_, 256, 0, stream>>>(X, W1, W2, A);
    syn_k_pv_mfma<<<dim3(N_ / 64, B_ * H_), 256, 0, stream>>>(A, Vthi, Vtlo, WV, Yhi, Ylo);
    syn_k_out_mfma<<<dim3((B_ * N_) / 64, F_ / 64), 256, 0, stream>>>(Yhi, Ylo, Whi, Wlo, Ob, out);
}